// Round 1
// baseline (5583.100 us; speedup 1.0000x reference)
//
#include <hip/hip_runtime.h>
#include <math.h>

#define NUSERS 100000
#define NITEMS 50000
#define BATCH  64
#define ORDER  8

// ---------------------------------------------------------------------------
// 32x32 LDS-tiled transpose: in[R][C] -> out[C][R]
// grid: (ceil(C/32), ceil(R/32)), block: (32,8)
// ---------------------------------------------------------------------------
__global__ void transpose_k(const float* __restrict__ in, float* __restrict__ out,
                            int R, int C) {
    __shared__ float tile[32][33];   // +1 pad: no LDS bank conflicts
    const int cb = blockIdx.x * 32;
    const int rb = blockIdx.y * 32;
    for (int i = threadIdx.y; i < 32; i += 8) {
        int r = rb + i, c = cb + threadIdx.x;
        if (r < R && c < C) tile[i][threadIdx.x] = in[(size_t)r * C + c];
    }
    __syncthreads();
    for (int i = threadIdx.y; i < 32; i += 8) {
        int c = cb + i, r = rb + threadIdx.x;
        if (c < C && r < R) out[(size_t)c * R + r] = tile[threadIdx.x][i];
    }
}

// ---------------------------------------------------------------------------
// Edge-parallel SpMM scatter: for each edge e, y[si[e]][lane] += v * x[gi[e]][lane]
// One wave (64 lanes) per edge iteration; lane indexes the batch dimension,
// so both the gather (x row) and the atomic scatter (y row) are 256 B
// fully-coalesced wave transactions.
// ---------------------------------------------------------------------------
__global__ void spmm_scatter(const float* __restrict__ vals,
                             const int*   __restrict__ gi,   // gather index into x
                             const int*   __restrict__ si,   // scatter index into y
                             const float* __restrict__ x,
                             float*       __restrict__ y,
                             int nnz) {
    const int lane = threadIdx.x & 63;
    const int wave = (blockIdx.x * blockDim.x + threadIdx.x) >> 6;
    const int nw   = (gridDim.x * blockDim.x) >> 6;
    for (int e = wave; e < nnz; e += nw) {
        float v = vals[e];
        int   g = gi[e];
        int   s = si[e];
        float xv = x[(size_t)g * BATCH + lane];
        atomicAdd(&y[(size_t)s * BATCH + lane], v * xv);
    }
}

// ---------------------------------------------------------------------------
// Chebyshev recurrence elementwise kernels over [NITEMS*BATCH]
// ---------------------------------------------------------------------------
// t1 = s - 2 z ;  out = c0*s + c1*t1
__global__ void combine_first(const float* __restrict__ s, const float* __restrict__ z,
                              float* __restrict__ t1, float* __restrict__ out,
                              float c0, float c1, int n) {
    int i = blockIdx.x * blockDim.x + threadIdx.x;
    if (i < n) {
        float sv = s[i];
        float t = sv - 2.0f * z[i];
        t1[i] = t;
        out[i] = c0 * sv + c1 * t;
    }
}

// t2 = 2*t1 - 4*z - t0 ;  out += ck*t2 ;  t2 overwrites the t0 buffer
__global__ void combine_k(const float* __restrict__ t1, float* __restrict__ t0t2,
                          const float* __restrict__ z, float* __restrict__ out,
                          float ck, int n) {
    int i = blockIdx.x * blockDim.x + threadIdx.x;
    if (i < n) {
        float t2 = 2.0f * t1[i] - 4.0f * z[i] - t0t2[i];
        t0t2[i] = t2;
        out[i] += ck * t2;
    }
}

// ---------------------------------------------------------------------------
// Host-side exact replica of the reference cheby_coeffs (double precision;
// np.round == round-half-even == default FP rounding of nearbyint)
// ---------------------------------------------------------------------------
static void cheby_coeffs_host(float* c) {
    const int order = ORDER, flatness = 2;
    const double PI = 3.14159265358979323846;
    double tgt[ORDER + 1], nodes[ORDER + 1];
    for (int x = 0; x <= order; ++x) {
        double xv = cos((double)(order - x) / order * PI);
        xv = nearbyint(xv * 1000.0) / 1000.0;
        double t = (xv < 0.0) ? pow(-xv, (double)flatness) * 0.5 + 0.5
                              : pow(xv, (double)flatness) * (-0.5) + 0.5;
        tgt[x] = nearbyint(t * 1000.0) / 1000.0;
    }
    for (int k = 1; k <= order + 1; ++k)
        nodes[k - 1] = cos((order + 1 + 0.5 - k) / (double)(order + 1) * PI);

    double prev[ORDER + 1], cur[ORDER + 1], nxt[ORDER + 1];
    double sums[ORDER + 1];
    double s0 = 0, s1 = 0;
    for (int i = 0; i <= order; ++i) {
        prev[i] = tgt[i];
        cur[i]  = nodes[i] * tgt[i];
        s0 += prev[i];
        s1 += cur[i];
    }
    sums[0] = s0; sums[1] = s1;
    for (int j = 2; j <= order; ++j) {
        double s = 0;
        for (int i = 0; i <= order; ++i) {
            nxt[i] = nodes[i] * cur[i] * 2.0 - prev[i];
            s += nxt[i];
        }
        sums[j] = s;
        for (int i = 0; i <= order; ++i) { prev[i] = cur[i]; cur[i] = nxt[i]; }
    }
    for (int j = 0; j <= order; ++j)
        c[j] = (float)(sums[j] * (2.0 / (order + 1)));
    c[0] *= 0.5f;
}

extern "C" void kernel_launch(void* const* d_in, const int* in_sizes, int n_in,
                              void* d_out, int out_size, void* d_ws, size_t ws_size,
                              hipStream_t stream) {
    const float* signal = (const float*)d_in[0];   // [BATCH, NITEMS]
    const float* vals   = (const float*)d_in[1];   // [NNZ]
    const int*   row    = (const int*)d_in[2];     // [NNZ] -> users
    const int*   col    = (const int*)d_in[3];     // [NNZ] -> items
    const int nnz = in_sizes[1];

    float* ws   = (float*)d_ws;
    const size_t NB = (size_t)NITEMS * BATCH;      // 3.2M floats
    float* bufA = ws;                               // t buffer (holds s initially)
    float* bufB = bufA + NB;                        // t buffer
    float* zbuf = bufB + NB;                        // z = A^T A x
    float* obuf = zbuf + NB;                        // Chebyshev accumulator [NITEMS,BATCH]
    float* ybuf = obuf + NB;                        // y = A x  [NUSERS,BATCH]

    float c[ORDER + 1];
    cheby_coeffs_host(c);

    const int n = (int)NB;
    const int eb = 256;                 // elementwise block
    const int ng = (n + eb - 1) / eb;
    const int sg = 8192;                // scatter grid (32768 waves, ~49 edges each)
    dim3 tb(32, 8);

    // s = signal^T  -> bufA [NITEMS, BATCH]
    transpose_k<<<dim3((NITEMS + 31) / 32, (BATCH + 31) / 32), tb, 0, stream>>>(
        signal, bufA, BATCH, NITEMS);

    // ---- k = 1: t1 = lap(s), out = c0*s + c1*t1 ----
    hipMemsetAsync(ybuf, 0, (size_t)NUSERS * BATCH * sizeof(float), stream);
    spmm_scatter<<<sg, 256, 0, stream>>>(vals, col, row, bufA, ybuf, nnz);
    hipMemsetAsync(zbuf, 0, NB * sizeof(float), stream);
    spmm_scatter<<<sg, 256, 0, stream>>>(vals, row, col, ybuf, zbuf, nnz);
    combine_first<<<ng, eb, 0, stream>>>(bufA, zbuf, bufB, obuf, c[0], c[1], n);

    float* t0 = bufA;
    float* t1 = bufB;
    for (int k = 2; k <= ORDER; ++k) {
        hipMemsetAsync(ybuf, 0, (size_t)NUSERS * BATCH * sizeof(float), stream);
        spmm_scatter<<<sg, 256, 0, stream>>>(vals, col, row, t1, ybuf, nnz);
        hipMemsetAsync(zbuf, 0, NB * sizeof(float), stream);
        spmm_scatter<<<sg, 256, 0, stream>>>(vals, row, col, ybuf, zbuf, nnz);
        combine_k<<<ng, eb, 0, stream>>>(t1, t0, zbuf, obuf, c[k], n);
        float* tmp = t0; t0 = t1; t1 = tmp;   // t0 <- old t1, t1 <- t2 (in old t0 buf)
    }

    // d_out = obuf^T : [NITEMS,BATCH] -> [BATCH,NITEMS]
    transpose_k<<<dim3((BATCH + 31) / 32, (NITEMS + 31) / 32), tb, 0, stream>>>(
        obuf, (float*)d_out, NITEMS, BATCH);
}

// Round 2
// 1843.042 us; speedup vs baseline: 3.0293x; 3.0293x over previous
//
#include <hip/hip_runtime.h>
#include <math.h>

#define NUSERS 100000
#define NITEMS 50000
#define BATCH  64
#define ORDER  8

// ---------------------------------------------------------------------------
// 32x32 LDS-tiled transpose: in[R][C] -> out[C][R]
// ---------------------------------------------------------------------------
__global__ void transpose_k(const float* __restrict__ in, float* __restrict__ out,
                            int R, int C) {
    __shared__ float tile[32][33];
    const int cb = blockIdx.x * 32;
    const int rb = blockIdx.y * 32;
    for (int i = threadIdx.y; i < 32; i += 8) {
        int r = rb + i, c = cb + threadIdx.x;
        if (r < R && c < C) tile[i][threadIdx.x] = in[(size_t)r * C + c];
    }
    __syncthreads();
    for (int i = threadIdx.y; i < 32; i += 8) {
        int c = cb + i, r = rb + threadIdx.x;
        if (c < C && r < R) out[(size_t)c * R + r] = tile[threadIdx.x][i];
    }
}

// ---------------------------------------------------------------------------
// CSR construction (rebuilt every launch; ws is re-poisoned by the harness)
// ---------------------------------------------------------------------------
__global__ void hist_k(const int* __restrict__ row, const int* __restrict__ col,
                       int* __restrict__ udeg, int* __restrict__ ideg, int nnz) {
    int i = blockIdx.x * blockDim.x + threadIdx.x;
    if (i < nnz) {
        atomicAdd(&udeg[row[i]], 1);
        atomicAdd(&ideg[col[i]], 1);
    }
}

// Single-block (1024 threads) exclusive prefix sum: deg[n] -> ptr[n+1], cur[n]=ptr[n]
__global__ void scan_k(const int* __restrict__ deg, int* __restrict__ ptr,
                       int* __restrict__ cur, int n) {
    __shared__ int ls[1024];
    const int tid = threadIdx.x;
    const int chunk = (n + 1023) >> 10;
    const int b = tid * chunk;
    const int e = min(b + chunk, n);
    int s = 0;
    for (int i = b; i < e; ++i) s += deg[i];
    ls[tid] = s;
    __syncthreads();
    for (int off = 1; off < 1024; off <<= 1) {
        int v = 0;
        if (tid >= off) v = ls[tid - off];
        __syncthreads();
        if (tid >= off) ls[tid] += v;
        __syncthreads();
    }
    int run = (tid == 0) ? 0 : ls[tid - 1];
    for (int i = b; i < e; ++i) {
        ptr[i] = run;
        cur[i] = run;
        run += deg[i];
    }
    if (tid == 1023) ptr[n] = ls[1023];
}

__global__ void fill_k(const int* __restrict__ row, const int* __restrict__ col,
                       const float* __restrict__ vals,
                       int* __restrict__ ucur, int* __restrict__ ucol, float* __restrict__ uval,
                       int* __restrict__ icur, int* __restrict__ irow, float* __restrict__ ival,
                       int nnz) {
    int i = blockIdx.x * blockDim.x + threadIdx.x;
    if (i < nnz) {
        int r = row[i], c = col[i];
        float v = vals[i];
        int p = atomicAdd(&ucur[r], 1);
        ucol[p] = c;
        uval[p] = v;
        int q = atomicAdd(&icur[c], 1);
        irow[q] = r;
        ival[q] = v;
    }
}

// ---------------------------------------------------------------------------
// Gather SpMM: one wave per output row, lane = batch element.
// y[r][lane] = sum_j val[j] * x[idx[j]][lane]  over j in [ptr[r], ptr[r+1])
// ptr/idx/val addresses are wave-uniform -> scalar loads; gathers are 256 B
// coalesced wave transactions. 4 accumulators for load-level ILP.
// ---------------------------------------------------------------------------
__global__ void spmm_csr(const int* __restrict__ ptr, const int* __restrict__ idx,
                         const float* __restrict__ val, const float* __restrict__ x,
                         float* __restrict__ y, int nrows) {
    const int lane = threadIdx.x & 63;
    const int r = (blockIdx.x * blockDim.x + threadIdx.x) >> 6;
    if (r >= nrows) return;
    const int b = ptr[r], e = ptr[r + 1];
    float a0 = 0.f, a1 = 0.f, a2 = 0.f, a3 = 0.f;
    int j = b;
    for (; j + 3 < e; j += 4) {
        a0 += val[j]     * x[(size_t)idx[j]     * BATCH + lane];
        a1 += val[j + 1] * x[(size_t)idx[j + 1] * BATCH + lane];
        a2 += val[j + 2] * x[(size_t)idx[j + 2] * BATCH + lane];
        a3 += val[j + 3] * x[(size_t)idx[j + 3] * BATCH + lane];
    }
    for (; j < e; ++j) a0 += val[j] * x[(size_t)idx[j] * BATCH + lane];
    y[(size_t)r * BATCH + lane] = (a0 + a1) + (a2 + a3);
}

// Second SpMM fused with the first Chebyshev combine:
// z = gather;  t1 = s - 2z;  out = c0*s + c1*t1
__global__ void spmm2_first(const int* __restrict__ ptr, const int* __restrict__ idx,
                            const float* __restrict__ val, const float* __restrict__ y,
                            const float* __restrict__ s, float* __restrict__ t1,
                            float* __restrict__ out, float c0, float c1, int nrows) {
    const int lane = threadIdx.x & 63;
    const int r = (blockIdx.x * blockDim.x + threadIdx.x) >> 6;
    if (r >= nrows) return;
    const int b = ptr[r], e = ptr[r + 1];
    float a0 = 0.f, a1 = 0.f, a2 = 0.f, a3 = 0.f;
    int j = b;
    for (; j + 3 < e; j += 4) {
        a0 += val[j]     * y[(size_t)idx[j]     * BATCH + lane];
        a1 += val[j + 1] * y[(size_t)idx[j + 1] * BATCH + lane];
        a2 += val[j + 2] * y[(size_t)idx[j + 2] * BATCH + lane];
        a3 += val[j + 3] * y[(size_t)idx[j + 3] * BATCH + lane];
    }
    for (; j < e; ++j) a0 += val[j] * y[(size_t)idx[j] * BATCH + lane];
    float z = (a0 + a1) + (a2 + a3);
    size_t i = (size_t)r * BATCH + lane;
    float sv = s[i];
    float t = sv - 2.0f * z;
    t1[i] = t;
    out[i] = c0 * sv + c1 * t;
}

// Second SpMM fused with general Chebyshev step:
// z = gather;  t2 = 2*t1 - 4*z - t0;  out += ck*t2;  t0t2 <- t2
__global__ void spmm2_k(const int* __restrict__ ptr, const int* __restrict__ idx,
                        const float* __restrict__ val, const float* __restrict__ y,
                        const float* __restrict__ t1, float* __restrict__ t0t2,
                        float* __restrict__ out, float ck, int nrows) {
    const int lane = threadIdx.x & 63;
    const int r = (blockIdx.x * blockDim.x + threadIdx.x) >> 6;
    if (r >= nrows) return;
    const int b = ptr[r], e = ptr[r + 1];
    float a0 = 0.f, a1 = 0.f, a2 = 0.f, a3 = 0.f;
    int j = b;
    for (; j + 3 < e; j += 4) {
        a0 += val[j]     * y[(size_t)idx[j]     * BATCH + lane];
        a1 += val[j + 1] * y[(size_t)idx[j + 1] * BATCH + lane];
        a2 += val[j + 2] * y[(size_t)idx[j + 2] * BATCH + lane];
        a3 += val[j + 3] * y[(size_t)idx[j + 3] * BATCH + lane];
    }
    for (; j < e; ++j) a0 += val[j] * y[(size_t)idx[j] * BATCH + lane];
    float z = (a0 + a1) + (a2 + a3);
    size_t i = (size_t)r * BATCH + lane;
    float t2 = 2.0f * t1[i] - 4.0f * z - t0t2[i];
    t0t2[i] = t2;
    out[i] += ck * t2;
}

// ---------------------------------------------------------------------------
// Host-side exact replica of reference cheby_coeffs
// ---------------------------------------------------------------------------
static void cheby_coeffs_host(float* c) {
    const int order = ORDER, flatness = 2;
    const double PI = 3.14159265358979323846;
    double tgt[ORDER + 1], nodes[ORDER + 1];
    for (int x = 0; x <= order; ++x) {
        double xv = cos((double)(order - x) / order * PI);
        xv = nearbyint(xv * 1000.0) / 1000.0;
        double t = (xv < 0.0) ? pow(-xv, (double)flatness) * 0.5 + 0.5
                              : pow(xv, (double)flatness) * (-0.5) + 0.5;
        tgt[x] = nearbyint(t * 1000.0) / 1000.0;
    }
    for (int k = 1; k <= order + 1; ++k)
        nodes[k - 1] = cos((order + 1 + 0.5 - k) / (double)(order + 1) * PI);

    double prev[ORDER + 1], cur[ORDER + 1], nxt[ORDER + 1];
    double sums[ORDER + 1];
    double s0 = 0, s1 = 0;
    for (int i = 0; i <= order; ++i) {
        prev[i] = tgt[i];
        cur[i]  = nodes[i] * tgt[i];
        s0 += prev[i];
        s1 += cur[i];
    }
    sums[0] = s0; sums[1] = s1;
    for (int j = 2; j <= order; ++j) {
        double s = 0;
        for (int i = 0; i <= order; ++i) {
            nxt[i] = nodes[i] * cur[i] * 2.0 - prev[i];
            s += nxt[i];
        }
        sums[j] = s;
        for (int i = 0; i <= order; ++i) { prev[i] = cur[i]; cur[i] = nxt[i]; }
    }
    for (int j = 0; j <= order; ++j)
        c[j] = (float)(sums[j] * (2.0 / (order + 1)));
    c[0] *= 0.5f;
}

extern "C" void kernel_launch(void* const* d_in, const int* in_sizes, int n_in,
                              void* d_out, int out_size, void* d_ws, size_t ws_size,
                              hipStream_t stream) {
    const float* signal = (const float*)d_in[0];   // [BATCH, NITEMS]
    const float* vals   = (const float*)d_in[1];   // [NNZ]
    const int*   row    = (const int*)d_in[2];     // [NNZ] -> users
    const int*   col    = (const int*)d_in[3];     // [NNZ] -> items
    const int nnz = in_sizes[1];

    // ---- workspace carving (all offsets in 4-byte units, 16B-aligned) ----
    char* wsb = (char*)d_ws;
    size_t off = 0;
    auto carve = [&](size_t nbytes) {
        void* p = wsb + off;
        off += (nbytes + 15) & ~(size_t)15;
        return p;
    };
    const size_t NB = (size_t)NITEMS * BATCH;      // 3.2M
    const size_t UB = (size_t)NUSERS * BATCH;      // 6.4M
    float* bufA = (float*)carve(NB * 4);           // s / t buffer
    float* bufB = (float*)carve(NB * 4);           // t buffer
    float* obuf = (float*)carve(NB * 4);           // accumulator
    float* ybuf = (float*)carve(UB * 4);           // y = A x
    int*   udeg = (int*)carve(NUSERS * 4);
    int*   ideg = (int*)carve(NITEMS * 4);
    int*   uptr = (int*)carve((NUSERS + 1) * 4);
    int*   ucur = (int*)carve(NUSERS * 4);
    int*   iptr = (int*)carve((NITEMS + 1) * 4);
    int*   icur = (int*)carve(NITEMS * 4);
    int*   ucol = (int*)carve((size_t)nnz * 4);
    float* uval = (float*)carve((size_t)nnz * 4);
    int*   irow = (int*)carve((size_t)nnz * 4);
    float* ival = (float*)carve((size_t)nnz * 4);
    (void)ws_size;

    float c[ORDER + 1];
    cheby_coeffs_host(c);

    // ---- CSR build ----
    hipMemsetAsync(udeg, 0, NUSERS * 4, stream);
    hipMemsetAsync(ideg, 0, NITEMS * 4, stream);
    hist_k<<<(nnz + 255) / 256, 256, 0, stream>>>(row, col, udeg, ideg, nnz);
    scan_k<<<1, 1024, 0, stream>>>(udeg, uptr, ucur, NUSERS);
    scan_k<<<1, 1024, 0, stream>>>(ideg, iptr, icur, NITEMS);
    fill_k<<<(nnz + 255) / 256, 256, 0, stream>>>(row, col, vals,
                                                  ucur, ucol, uval,
                                                  icur, irow, ival, nnz);

    // ---- s = signal^T ----
    dim3 tb(32, 8);
    transpose_k<<<dim3((NITEMS + 31) / 32, (BATCH + 31) / 32), tb, 0, stream>>>(
        signal, bufA, BATCH, NITEMS);

    const int ug = (NUSERS * 64 + 255) / 256;   // one wave per user row
    const int ig = (NITEMS * 64 + 255) / 256;   // one wave per item row

    // ---- k = 1 ----
    spmm_csr<<<ug, 256, 0, stream>>>(uptr, ucol, uval, bufA, ybuf, NUSERS);
    spmm2_first<<<ig, 256, 0, stream>>>(iptr, irow, ival, ybuf, bufA, bufB, obuf,
                                        c[0], c[1], NITEMS);

    float* t0 = bufA;
    float* t1 = bufB;
    for (int k = 2; k <= ORDER; ++k) {
        spmm_csr<<<ug, 256, 0, stream>>>(uptr, ucol, uval, t1, ybuf, NUSERS);
        spmm2_k<<<ig, 256, 0, stream>>>(iptr, irow, ival, ybuf, t1, t0, obuf,
                                        c[k], NITEMS);
        float* tmp = t0; t0 = t1; t1 = tmp;
    }

    // ---- d_out = obuf^T ----
    transpose_k<<<dim3((BATCH + 31) / 32, (NITEMS + 31) / 32), tb, 0, stream>>>(
        obuf, (float*)d_out, NITEMS, BATCH);
}

// Round 3
// 1623.799 us; speedup vs baseline: 3.4383x; 1.1350x over previous
//
#include <hip/hip_runtime.h>
#include <math.h>

#define NUSERS 100000
#define NITEMS 50000
#define BATCH  64
#define ORDER  8
#define SCAN_BLOCKS 256

// Packed edge: gather index + value, one 8B unit
struct __align__(8) Edge { int idx; float val; };

// ---------------------------------------------------------------------------
// 32x32 LDS-tiled transpose: in[R][C] -> out[C][R]
// ---------------------------------------------------------------------------
__global__ void transpose_k(const float* __restrict__ in, float* __restrict__ out,
                            int R, int C) {
    __shared__ float tile[32][33];
    const int cb = blockIdx.x * 32;
    const int rb = blockIdx.y * 32;
    for (int i = threadIdx.y; i < 32; i += 8) {
        int r = rb + i, c = cb + threadIdx.x;
        if (r < R && c < C) tile[i][threadIdx.x] = in[(size_t)r * C + c];
    }
    __syncthreads();
    for (int i = threadIdx.y; i < 32; i += 8) {
        int c = cb + i, r = rb + threadIdx.x;
        if (c < C && r < R) out[(size_t)c * R + r] = tile[threadIdx.x][i];
    }
}

// ---------------------------------------------------------------------------
// CSR construction
// ---------------------------------------------------------------------------
__global__ void hist_k(const int* __restrict__ row, const int* __restrict__ col,
                       int* __restrict__ udeg, int* __restrict__ ideg, int nnz) {
    int i = blockIdx.x * blockDim.x + threadIdx.x;
    if (i < nnz) {
        atomicAdd(&udeg[row[i]], 1);
        atomicAdd(&ideg[col[i]], 1);
    }
}

// Phase A: per-block partial sums over contiguous chunks (coalesced)
__global__ void scan_partial(const int* __restrict__ deg, int* __restrict__ bsum, int n) {
    __shared__ int ls[256];
    const int chunk = (n + SCAN_BLOCKS - 1) / SCAN_BLOCKS;
    const int b0 = blockIdx.x * chunk;
    const int e0 = min(b0 + chunk, n);
    int s = 0;
    for (int i = b0 + threadIdx.x; i < e0; i += 256) s += deg[i];
    ls[threadIdx.x] = s;
    __syncthreads();
    for (int off = 128; off > 0; off >>= 1) {
        if (threadIdx.x < off) ls[threadIdx.x] += ls[threadIdx.x + off];
        __syncthreads();
    }
    if (threadIdx.x == 0) bsum[blockIdx.x] = ls[0];
}

// Phase B: exclusive scan of the SCAN_BLOCKS block sums (single block)
__global__ void scan_bsum(const int* __restrict__ bsum, int* __restrict__ bofs) {
    __shared__ int ls[SCAN_BLOCKS];
    const int t = threadIdx.x;
    int v = bsum[t];
    ls[t] = v;
    __syncthreads();
    for (int off = 1; off < SCAN_BLOCKS; off <<= 1) {
        int u = (t >= off) ? ls[t - off] : 0;
        __syncthreads();
        ls[t] += u;
        __syncthreads();
    }
    bofs[t] = ls[t] - v;   // exclusive
}

// Phase C: per-block local exclusive scan + global offset -> ptr, cur
__global__ void scan_final(const int* __restrict__ deg, const int* __restrict__ bofs,
                           int* __restrict__ ptr, int* __restrict__ cur, int n) {
    __shared__ int ls[256];
    const int chunk = (n + SCAN_BLOCKS - 1) / SCAN_BLOCKS;
    const int b0 = blockIdx.x * chunk;
    const int e0 = min(b0 + chunk, n);
    int carry = bofs[blockIdx.x];
    for (int base = b0; base < e0; base += 256) {
        int i = base + threadIdx.x;
        int v = (i < e0) ? deg[i] : 0;
        ls[threadIdx.x] = v;
        __syncthreads();
        for (int off = 1; off < 256; off <<= 1) {
            int u = (threadIdx.x >= off) ? ls[threadIdx.x - off] : 0;
            __syncthreads();
            ls[threadIdx.x] += u;
            __syncthreads();
        }
        if (i < e0) {
            int excl = carry + ls[threadIdx.x] - v;
            ptr[i] = excl;
            cur[i] = excl;
        }
        int tilesum = ls[255];
        __syncthreads();
        carry += tilesum;
    }
    if (blockIdx.x == SCAN_BLOCKS - 1 && threadIdx.x == 0)
        ptr[n] = carry;    // carry is block-uniform; last block ends at n
}

// Fill both CSR edge arrays: one 8B packed write per direction per edge
__global__ void fill_k(const int* __restrict__ row, const int* __restrict__ col,
                       const float* __restrict__ vals,
                       int* __restrict__ ucur, Edge* __restrict__ uedge,
                       int* __restrict__ icur, Edge* __restrict__ iedge,
                       int nnz) {
    int i = blockIdx.x * blockDim.x + threadIdx.x;
    if (i < nnz) {
        int r = row[i], c = col[i];
        float v = vals[i];
        int p = atomicAdd(&ucur[r], 1);
        uedge[p] = Edge{c, v};
        int q = atomicAdd(&icur[c], 1);
        iedge[q] = Edge{r, v};
    }
}

// ---------------------------------------------------------------------------
// Gather SpMM: one wave per output row, lane = batch element.
// ---------------------------------------------------------------------------
__global__ void spmm_csr(const int* __restrict__ ptr, const Edge* __restrict__ ed,
                         const float* __restrict__ x, float* __restrict__ y, int nrows) {
    const int lane = threadIdx.x & 63;
    const int r = (blockIdx.x * blockDim.x + threadIdx.x) >> 6;
    if (r >= nrows) return;
    const int b = ptr[r], e = ptr[r + 1];
    float a0 = 0.f, a1 = 0.f, a2 = 0.f, a3 = 0.f;
    int j = b;
    for (; j + 3 < e; j += 4) {
        Edge e0 = ed[j], e1 = ed[j + 1], e2 = ed[j + 2], e3 = ed[j + 3];
        a0 += e0.val * x[(size_t)e0.idx * BATCH + lane];
        a1 += e1.val * x[(size_t)e1.idx * BATCH + lane];
        a2 += e2.val * x[(size_t)e2.idx * BATCH + lane];
        a3 += e3.val * x[(size_t)e3.idx * BATCH + lane];
    }
    for (; j < e; ++j) { Edge eo = ed[j]; a0 += eo.val * x[(size_t)eo.idx * BATCH + lane]; }
    y[(size_t)r * BATCH + lane] = (a0 + a1) + (a2 + a3);
}

// Second SpMM fused with first Chebyshev combine: t1 = s-2z; out = c0*s+c1*t1
__global__ void spmm2_first(const int* __restrict__ ptr, const Edge* __restrict__ ed,
                            const float* __restrict__ y, const float* __restrict__ s,
                            float* __restrict__ t1, float* __restrict__ out,
                            float c0, float c1, int nrows) {
    const int lane = threadIdx.x & 63;
    const int r = (blockIdx.x * blockDim.x + threadIdx.x) >> 6;
    if (r >= nrows) return;
    const int b = ptr[r], e = ptr[r + 1];
    float a0 = 0.f, a1 = 0.f, a2 = 0.f, a3 = 0.f;
    int j = b;
    for (; j + 3 < e; j += 4) {
        Edge e0 = ed[j], e1 = ed[j + 1], e2 = ed[j + 2], e3 = ed[j + 3];
        a0 += e0.val * y[(size_t)e0.idx * BATCH + lane];
        a1 += e1.val * y[(size_t)e1.idx * BATCH + lane];
        a2 += e2.val * y[(size_t)e2.idx * BATCH + lane];
        a3 += e3.val * y[(size_t)e3.idx * BATCH + lane];
    }
    for (; j < e; ++j) { Edge eo = ed[j]; a0 += eo.val * y[(size_t)eo.idx * BATCH + lane]; }
    float z = (a0 + a1) + (a2 + a3);
    size_t i = (size_t)r * BATCH + lane;
    float sv = s[i];
    float t = sv - 2.0f * z;
    t1[i] = t;
    out[i] = c0 * sv + c1 * t;
}

// Second SpMM fused with general step: t2 = 2*t1-4*z-t0; out += ck*t2; t0 <- t2
__global__ void spmm2_k(const int* __restrict__ ptr, const Edge* __restrict__ ed,
                        const float* __restrict__ y, const float* __restrict__ t1,
                        float* __restrict__ t0t2, float* __restrict__ out,
                        float ck, int nrows) {
    const int lane = threadIdx.x & 63;
    const int r = (blockIdx.x * blockDim.x + threadIdx.x) >> 6;
    if (r >= nrows) return;
    const int b = ptr[r], e = ptr[r + 1];
    float a0 = 0.f, a1 = 0.f, a2 = 0.f, a3 = 0.f;
    int j = b;
    for (; j + 3 < e; j += 4) {
        Edge e0 = ed[j], e1 = ed[j + 1], e2 = ed[j + 2], e3 = ed[j + 3];
        a0 += e0.val * y[(size_t)e0.idx * BATCH + lane];
        a1 += e1.val * y[(size_t)e1.idx * BATCH + lane];
        a2 += e2.val * y[(size_t)e2.idx * BATCH + lane];
        a3 += e3.val * y[(size_t)e3.idx * BATCH + lane];
    }
    for (; j < e; ++j) { Edge eo = ed[j]; a0 += eo.val * y[(size_t)eo.idx * BATCH + lane]; }
    float z = (a0 + a1) + (a2 + a3);
    size_t i = (size_t)r * BATCH + lane;
    float t2 = 2.0f * t1[i] - 4.0f * z - t0t2[i];
    t0t2[i] = t2;
    out[i] += ck * t2;
}

// ---------------------------------------------------------------------------
// Host-side exact replica of reference cheby_coeffs
// ---------------------------------------------------------------------------
static void cheby_coeffs_host(float* c) {
    const int order = ORDER, flatness = 2;
    const double PI = 3.14159265358979323846;
    double tgt[ORDER + 1], nodes[ORDER + 1];
    for (int x = 0; x <= order; ++x) {
        double xv = cos((double)(order - x) / order * PI);
        xv = nearbyint(xv * 1000.0) / 1000.0;
        double t = (xv < 0.0) ? pow(-xv, (double)flatness) * 0.5 + 0.5
                              : pow(xv, (double)flatness) * (-0.5) + 0.5;
        tgt[x] = nearbyint(t * 1000.0) / 1000.0;
    }
    for (int k = 1; k <= order + 1; ++k)
        nodes[k - 1] = cos((order + 1 + 0.5 - k) / (double)(order + 1) * PI);

    double prev[ORDER + 1], cur[ORDER + 1], nxt[ORDER + 1];
    double sums[ORDER + 1];
    double s0 = 0, s1 = 0;
    for (int i = 0; i <= order; ++i) {
        prev[i] = tgt[i];
        cur[i]  = nodes[i] * tgt[i];
        s0 += prev[i];
        s1 += cur[i];
    }
    sums[0] = s0; sums[1] = s1;
    for (int j = 2; j <= order; ++j) {
        double s = 0;
        for (int i = 0; i <= order; ++i) {
            nxt[i] = nodes[i] * cur[i] * 2.0 - prev[i];
            s += nxt[i];
        }
        sums[j] = s;
        for (int i = 0; i <= order; ++i) { prev[i] = cur[i]; cur[i] = nxt[i]; }
    }
    for (int j = 0; j <= order; ++j)
        c[j] = (float)(sums[j] * (2.0 / (order + 1)));
    c[0] *= 0.5f;
}

extern "C" void kernel_launch(void* const* d_in, const int* in_sizes, int n_in,
                              void* d_out, int out_size, void* d_ws, size_t ws_size,
                              hipStream_t stream) {
    const float* signal = (const float*)d_in[0];   // [BATCH, NITEMS]
    const float* vals   = (const float*)d_in[1];   // [NNZ]
    const int*   row    = (const int*)d_in[2];     // [NNZ] -> users
    const int*   col    = (const int*)d_in[3];     // [NNZ] -> items
    const int nnz = in_sizes[1];

    char* wsb = (char*)d_ws;
    size_t off = 0;
    auto carve = [&](size_t nbytes) {
        void* p = wsb + off;
        off += (nbytes + 15) & ~(size_t)15;
        return p;
    };
    const size_t NB = (size_t)NITEMS * BATCH;
    const size_t UB = (size_t)NUSERS * BATCH;
    float* bufA = (float*)carve(NB * 4);
    float* bufB = (float*)carve(NB * 4);
    float* obuf = (float*)carve(NB * 4);
    float* ybuf = (float*)carve(UB * 4);
    int*   udeg = (int*)carve(NUSERS * 4);          // NUSERS*4 is 16B-multiple:
    int*   ideg = (int*)carve(NITEMS * 4);          // udeg/ideg contiguous
    int*   uptr = (int*)carve((NUSERS + 1) * 4);
    int*   ucur = (int*)carve(NUSERS * 4);
    int*   iptr = (int*)carve((NITEMS + 1) * 4);
    int*   icur = (int*)carve(NITEMS * 4);
    int*   bsum = (int*)carve(SCAN_BLOCKS * 4);
    int*   bofs = (int*)carve(SCAN_BLOCKS * 4);
    Edge*  uedge = (Edge*)carve((size_t)nnz * 8);
    Edge*  iedge = (Edge*)carve((size_t)nnz * 8);
    (void)ws_size;

    float c[ORDER + 1];
    cheby_coeffs_host(c);

    // ---- CSR build ----
    hipMemsetAsync(udeg, 0, (size_t)(NUSERS + NITEMS) * 4, stream);  // udeg+ideg adjacent
    hist_k<<<(nnz + 255) / 256, 256, 0, stream>>>(row, col, udeg, ideg, nnz);

    scan_partial<<<SCAN_BLOCKS, 256, 0, stream>>>(udeg, bsum, NUSERS);
    scan_bsum<<<1, SCAN_BLOCKS, 0, stream>>>(bsum, bofs);
    scan_final<<<SCAN_BLOCKS, 256, 0, stream>>>(udeg, bofs, uptr, ucur, NUSERS);

    scan_partial<<<SCAN_BLOCKS, 256, 0, stream>>>(ideg, bsum, NITEMS);
    scan_bsum<<<1, SCAN_BLOCKS, 0, stream>>>(bsum, bofs);
    scan_final<<<SCAN_BLOCKS, 256, 0, stream>>>(ideg, bofs, iptr, icur, NITEMS);

    fill_k<<<(nnz + 255) / 256, 256, 0, stream>>>(row, col, vals,
                                                  ucur, uedge, icur, iedge, nnz);

    // ---- s = signal^T ----
    dim3 tb(32, 8);
    transpose_k<<<dim3((NITEMS + 31) / 32, (BATCH + 31) / 32), tb, 0, stream>>>(
        signal, bufA, BATCH, NITEMS);

    const int ug = (NUSERS * 64 + 255) / 256;
    const int ig = (NITEMS * 64 + 255) / 256;

    // ---- k = 1 ----
    spmm_csr<<<ug, 256, 0, stream>>>(uptr, uedge, bufA, ybuf, NUSERS);
    spmm2_first<<<ig, 256, 0, stream>>>(iptr, iedge, ybuf, bufA, bufB, obuf,
                                        c[0], c[1], NITEMS);

    float* t0 = bufA;
    float* t1 = bufB;
    for (int k = 2; k <= ORDER; ++k) {
        spmm_csr<<<ug, 256, 0, stream>>>(uptr, uedge, t1, ybuf, NUSERS);
        spmm2_k<<<ig, 256, 0, stream>>>(iptr, iedge, ybuf, t1, t0, obuf,
                                        c[k], NITEMS);
        float* tmp = t0; t0 = t1; t1 = tmp;
    }

    // ---- d_out = obuf^T ----
    transpose_k<<<dim3((BATCH + 31) / 32, (NITEMS + 31) / 32), tb, 0, stream>>>(
        obuf, (float*)d_out, NITEMS, BATCH);
}